// Round 4
// baseline (93.249 us; speedup 1.0000x reference)
//
#include <hip/hip_runtime.h>
#include <math.h>

// Problem constants (setup_inputs is fixed: P=4, A=4096)
#define A_ATOMS 4096
#define P_POSES 4
#define N_TOT   (A_ATOMS * P_POSES)
#define TILE    128
#define NTILES  (A_ATOMS / TILE)             // 32
#define NPAIRT  (NTILES * (NTILES + 1) / 2)  // 528 upper-tri tiles per pose

// forward-kinematics segmented scan geometry
#define SEG     64                            // atoms per segment = 1 wave
#define NSEG    (A_ATOMS / SEG)               // 64 segments per pose
#define NSEG_TOT (P_POSES * NSEG)             // 256 global segments

typedef float v2f __attribute__((ext_vector_type(2)));

__device__ __constant__ float c_SIGMA2  = 1.9f * 1.9f;
__device__ __constant__ float c_4EPS    = 0.8f;   // 4 * 0.2
__device__ __constant__ float c_R2SOFT  = 0.25f;

// ---------------- rigid transform (3x4 row-major: r|t) ----------------
struct RT { float m[12]; };

__device__ inline RT rt_identity() {
    RT v;
    v.m[0]=1.f; v.m[1]=0.f; v.m[2]=0.f;  v.m[3]=0.f;
    v.m[4]=0.f; v.m[5]=1.f; v.m[6]=0.f;  v.m[7]=0.f;
    v.m[8]=0.f; v.m[9]=0.f; v.m[10]=1.f; v.m[11]=0.f;
    return v;
}

// C = A o B  (left-to-right chain product: cum = cum @ ht)
__device__ inline RT rt_compose(const RT& a, const RT& b) {
    RT c;
#pragma unroll
    for (int i = 0; i < 3; ++i) {
        float a0 = a.m[i*4+0], a1 = a.m[i*4+1], a2 = a.m[i*4+2];
        c.m[i*4+0] = fmaf(a0, b.m[0], fmaf(a1, b.m[4],  a2*b.m[8]));
        c.m[i*4+1] = fmaf(a0, b.m[1], fmaf(a1, b.m[5],  a2*b.m[9]));
        c.m[i*4+2] = fmaf(a0, b.m[2], fmaf(a1, b.m[6],  a2*b.m[10]));
        c.m[i*4+3] = fmaf(a0, b.m[3], fmaf(a1, b.m[7],  fmaf(a2, b.m[11], a.m[i*4+3])));
    }
    return c;
}

// lane-wise pull of an RT from (lane - off) within the wave
__device__ inline RT rt_shfl_up(const RT& a, int off) {
    RT r;
#pragma unroll
    for (int i = 0; i < 12; ++i) r.m[i] = __shfl_up(a.m[i], off, 64);
    return r;
}

// Accurate trig kept on purpose: the 4096-long compose chain amplifies per-HT
// error; absmax margin vs threshold is only ~2.2x.
__device__ inline RT local_ht(const float* __restrict__ dof) {
    float phi = dof[0], th = dof[1];
    float d = fmaf(0.25f, tanhf(dof[2]), 1.5f);
    float sp, cp, st, ct;
    sincosf(phi, &sp, &cp);
    sincosf(th,  &st, &ct);
    RT h;
    h.m[0] = cp*ct; h.m[1] = -sp; h.m[2]  = cp*st; h.m[3]  = d*cp*ct;
    h.m[4] = sp*ct; h.m[5] =  cp; h.m[6]  = sp*st; h.m[7]  = d*sp*ct;
    h.m[8] = -st;   h.m[9] = 0.f; h.m[10] = ct;    h.m[11] = -d*st;
    return h;
}

// ---------------- kernel 1a: per-segment inclusive scan (wave-level, no LDS) ----
// 256 blocks x 64 threads: one wave per 64-atom segment (1 seg/wave keeps VGPR
// pressure low — the R2 fused variant spilled under launch_bounds(1024)).
// Output: per atom, a packed float4 (rel_tx, rel_ty, rel_tz, global_seg_id)
// scattered directly through kid. Carrying the seg id with the atom keeps
// correctness for ANY kid permutation (no identity assumption); lj applies
// E[seg] at staging time. fk_apply's 384 KB X/Y/Z round-trip is gone.
__global__ __launch_bounds__(SEG) void fk_scan(const float* __restrict__ dofs,
                                               const int* __restrict__ kid,
                                               float4* __restrict__ TS,
                                               float4* __restrict__ S0,
                                               float4* __restrict__ S1,
                                               float4* __restrict__ S2) {
    const int pose = blockIdx.x >> 6;        // NSEG = 64
    const int seg  = blockIdx.x & (NSEG - 1);
    const int lane = threadIdx.x;
    const int g    = pose * A_ATOMS + seg * SEG + lane;

    RT v = local_ht(dofs + (size_t)g * 9);

    // inclusive wave scan, earlier lane on the LEFT
#pragma unroll
    for (int off = 1; off < 64; off <<= 1) {
        RT l = rt_shfl_up(v, off);
        if (lane >= off) v = rt_compose(l, v);
    }

    const int wseg = pose * NSEG + seg;      // global segment id, travels with atom
    TS[kid[g]] = make_float4(v.m[3], v.m[7], v.m[11], __int_as_float(wseg));

    // segment total (full RT)
    if (lane == 63) {
        S0[wseg] = make_float4(v.m[0], v.m[1], v.m[2],  v.m[3]);
        S1[wseg] = make_float4(v.m[4], v.m[5], v.m[6],  v.m[7]);
        S2[wseg] = make_float4(v.m[8], v.m[9], v.m[10], v.m[11]);
    }
}

// ---------------- kernel 1b: tiny totals-scan -> exclusive prefix table E --------
// 4 blocks x 64 lanes (one wave per pose). Replaces the former 16k-thread
// fk_apply: the per-atom apply (9 FMA) moved into lj's staging where it is
// issue-free. Also zeroes out[pose] ahead of lj's atomicAdd (stream-ordered).
__global__ __launch_bounds__(SEG) void fk_eprefix(const float4* __restrict__ S0,
                                                  const float4* __restrict__ S1,
                                                  const float4* __restrict__ S2,
                                                  float4* __restrict__ E0,
                                                  float4* __restrict__ E1,
                                                  float4* __restrict__ E2,
                                                  float* __restrict__ out) {
    const int pose = blockIdx.x;
    const int lane = threadIdx.x;
    if (lane == 0) out[pose] = 0.f;

    const int s = pose * NSEG + lane;
    float4 a0 = S0[s], a1 = S1[s], a2 = S2[s];
    RT v;
    v.m[0]=a0.x; v.m[1]=a0.y; v.m[2]=a0.z;  v.m[3]=a0.w;
    v.m[4]=a1.x; v.m[5]=a1.y; v.m[6]=a1.z;  v.m[7]=a1.w;
    v.m[8]=a2.x; v.m[9]=a2.y; v.m[10]=a2.z; v.m[11]=a2.w;
#pragma unroll
    for (int off = 1; off < 64; off <<= 1) {
        RT l = rt_shfl_up(v, off);
        if (lane >= off) v = rt_compose(l, v);
    }
    // exclusive prefix: shift right by one, identity at segment 0
    RT ex = rt_shfl_up(v, 1);
    if (lane == 0) ex = rt_identity();
    E0[s] = make_float4(ex.m[0], ex.m[1], ex.m[2],  ex.m[3]);
    E1[s] = make_float4(ex.m[4], ex.m[5], ex.m[6],  ex.m[7]);
    E2[s] = make_float4(ex.m[8], ex.m[9], ex.m[10], ex.m[11]);
}

// ---------------- kernel 2: pairwise LJ over upper-triangular tiles ----------------
// Staging now resolves final coordinates inline: coord = E[wseg].R * t_rel +
// E[wseg].t (9 FMA/atom). With aligned 64-atom segments the E loads are
// wave-uniform L2 broadcasts. Compute loops unchanged from verified baseline.
__global__ __launch_bounds__(256) void lj_kernel(const float4* __restrict__ TS,
                                                 const float4* __restrict__ E0,
                                                 const float4* __restrict__ E1,
                                                 const float4* __restrict__ E2,
                                                 float* __restrict__ out) {
    const int pose = blockIdx.y;
    // map blockIdx.x -> (bi, bj) with bi <= bj
    int rr = blockIdx.x, bi = 0;
    while (rr >= NTILES - bi) { rr -= NTILES - bi; ++bi; }
    const int bj = bi + rr;

    __shared__ float sxi[TILE], syi[TILE], szi[TILE];
    __shared__ float sxj[TILE], syj[TILE], szj[TILE];

    const int tid = threadIdx.x;
    {
        const int a_loc = (tid < TILE) ? (bi * TILE + tid) : (bj * TILE + (tid - TILE));
        float4 t4 = TS[pose * A_ATOMS + a_loc];
        const int wseg = __float_as_int(t4.w);
        float4 x0 = E0[wseg], x1 = E1[wseg], x2 = E2[wseg];
        float x = fmaf(x0.x, t4.x, fmaf(x0.y, t4.y, fmaf(x0.z, t4.z, x0.w)));
        float y = fmaf(x1.x, t4.x, fmaf(x1.y, t4.y, fmaf(x1.z, t4.z, x1.w)));
        float z = fmaf(x2.x, t4.x, fmaf(x2.y, t4.y, fmaf(x2.z, t4.z, x2.w)));
        if (tid < TILE) { sxi[tid] = x; syi[tid] = y; szi[tid] = z; }
        else            { sxj[tid - TILE] = x; syj[tid - TILE] = y; szj[tid - TILE] = z; }
    }
    __syncthreads();

    // 16 i-groups x 16 j-groups; each thread: 8 i-rows x 8 j-cols in registers
    const int i0 = (tid & 15) * 8;
    const int j0 = (tid >> 4) * 8;

    const float SIG2 = c_SIGMA2, SOFT = c_R2SOFT;
    float acc = 0.f;

    if (bi != bj) {
        // off-diagonal tile (496/528): packed fp32 pairs -> v_pk_fma_f32 candidates
        float xi[8], yi[8], zi[8];
#pragma unroll
        for (int k = 0; k < 8; ++k) {
            xi[k] = sxi[i0 + k]; yi[k] = syi[i0 + k]; zi[k] = szi[i0 + k];
        }
        v2f xj2[4], yj2[4], zj2[4];
#pragma unroll
        for (int p = 0; p < 4; ++p) {
            xj2[p] = (v2f){sxj[j0 + 2*p], sxj[j0 + 2*p + 1]};
            yj2[p] = (v2f){syj[j0 + 2*p], syj[j0 + 2*p + 1]};
            zj2[p] = (v2f){szj[j0 + 2*p], szj[j0 + 2*p + 1]};
        }
        const v2f soft2 = (v2f){SOFT, SOFT};
        v2f acc2 = (v2f){0.f, 0.f};
#pragma unroll
        for (int p = 0; p < 4; ++p) {
#pragma unroll
            for (int k = 0; k < 8; ++k) {
                v2f dx = xi[k] - xj2[p];
                v2f dy = yi[k] - yj2[p];
                v2f dz = zi[k] - zj2[p];
                v2f r2 = __builtin_elementwise_fma(dx, dx,
                         __builtin_elementwise_fma(dy, dy,
                         __builtin_elementwise_fma(dz, dz, soft2)));
                v2f rc = (v2f){__builtin_amdgcn_rcpf(r2.x), __builtin_amdgcn_rcpf(r2.y)};
                v2f t  = SIG2 * rc;
                v2f i6 = t * t * t;
                acc2 += __builtin_elementwise_fma(i6, i6, -i6);   // inv12 - inv6
            }
        }
        acc = acc2.x + acc2.y;
    } else {
        // diagonal tile: keep only i < j (scalar masked path)
        float xi[8], yi[8], zi[8], xj[8], yj[8], zj[8];
#pragma unroll
        for (int k = 0; k < 8; ++k) {
            xi[k] = sxi[i0 + k]; yi[k] = syi[i0 + k]; zi[k] = szi[i0 + k];
            xj[k] = sxj[j0 + k]; yj[k] = syj[j0 + k]; zj[k] = szj[j0 + k];
        }
#pragma unroll
        for (int jj = 0; jj < 8; ++jj) {
            int j = j0 + jj;
#pragma unroll
            for (int k = 0; k < 8; ++k) {
                float dx = xi[k] - xj[jj], dy = yi[k] - yj[jj], dz = zi[k] - zj[jj];
                float r2 = fmaf(dx, dx, fmaf(dy, dy, fmaf(dz, dz, SOFT)));
                float t  = SIG2 * __builtin_amdgcn_rcpf(r2);
                float i6 = t * t * t;
                float hh = fmaf(i6, i6, -i6);
                acc += ((i0 + k) < j) ? hh : 0.f;
            }
        }
    }
    acc *= c_4EPS;

    // wave64 reduce then cross-wave via LDS
#pragma unroll
    for (int off = 32; off > 0; off >>= 1) acc += __shfl_down(acc, off, 64);

    __shared__ float wsum[4];
    int lane = tid & 63, wid = tid >> 6;
    if (lane == 0) wsum[wid] = acc;
    __syncthreads();
    if (tid == 0) {
        float s = wsum[0] + wsum[1] + wsum[2] + wsum[3];
        atomicAdd(out + pose, s);
    }
}

// ---------------- launch ----------------
extern "C" void kernel_launch(void* const* d_in, const int* in_sizes, int n_in,
                              void* d_out, int out_size, void* d_ws, size_t ws_size,
                              hipStream_t stream) {
    (void)in_sizes; (void)n_in; (void)out_size; (void)ws_size;
    const float* dofs = (const float*)d_in[0];
    const int*   kid  = (const int*)d_in[2];
    float*       out  = (float*)d_out;

    // workspace layout (16B-aligned):
    //   TS:        N_TOT float4  (rel translation + seg id, kid-scattered) 256 KB
    //   S0,S1,S2:  3 * NSEG_TOT float4 (segment totals)                     12 KB
    //   E0,E1,E2:  3 * NSEG_TOT float4 (exclusive prefixes)                 12 KB
    float4* TS = (float4*)d_ws;
    float4* S0 = TS + N_TOT;
    float4* S1 = S0 + NSEG_TOT;
    float4* S2 = S1 + NSEG_TOT;
    float4* E0 = S2 + NSEG_TOT;
    float4* E1 = E0 + NSEG_TOT;
    float4* E2 = E1 + NSEG_TOT;

    fk_scan<<<NSEG_TOT, SEG, 0, stream>>>(dofs, kid, TS, S0, S1, S2);
    fk_eprefix<<<P_POSES, SEG, 0, stream>>>(S0, S1, S2, E0, E1, E2, out);
    dim3 grid(NPAIRT, P_POSES);
    lj_kernel<<<grid, 256, 0, stream>>>(TS, E0, E1, E2, out);
}

// Round 5
// 76.841 us; speedup vs baseline: 1.2135x; 1.2135x over previous
//
#include <hip/hip_runtime.h>
#include <math.h>

// Problem constants (setup_inputs is fixed: P=4, A=4096)
#define A_ATOMS 4096
#define P_POSES 4
#define N_TOT   (A_ATOMS * P_POSES)
#define TILE    128
#define NTILES  (A_ATOMS / TILE)             // 32
#define JG      4                            // j-tiles per block (128x512 strip)
#define NJG     (NTILES / JG)                // 8 aligned j-groups
// groups per row bi: NJG - bi/JG; total per pose = sum = 144
#define NSTRIPS 144

// forward-kinematics segmented scan geometry (verified R3 structure)
#define SEG     64                            // atoms per segment = 1 wave
#define NSEG    (A_ATOMS / SEG)               // 64 segments per pose
#define APPLY_T 256                           // fk_apply threads (1 atom/thread)
#define APPLY_B (A_ATOMS / APPLY_T)           // 16 blocks per pose

typedef float v2f __attribute__((ext_vector_type(2)));

__device__ __constant__ float c_SIGMA2  = 1.9f * 1.9f;
__device__ __constant__ float c_4EPS    = 0.8f;   // 4 * 0.2
__device__ __constant__ float c_R2SOFT  = 0.25f;

// ---------------- rigid transform (3x4 row-major: r|t) ----------------
struct RT { float m[12]; };

__device__ inline RT rt_identity() {
    RT v;
    v.m[0]=1.f; v.m[1]=0.f; v.m[2]=0.f;  v.m[3]=0.f;
    v.m[4]=0.f; v.m[5]=1.f; v.m[6]=0.f;  v.m[7]=0.f;
    v.m[8]=0.f; v.m[9]=0.f; v.m[10]=1.f; v.m[11]=0.f;
    return v;
}

// C = A o B  (left-to-right chain product: cum = cum @ ht)
__device__ inline RT rt_compose(const RT& a, const RT& b) {
    RT c;
#pragma unroll
    for (int i = 0; i < 3; ++i) {
        float a0 = a.m[i*4+0], a1 = a.m[i*4+1], a2 = a.m[i*4+2];
        c.m[i*4+0] = fmaf(a0, b.m[0], fmaf(a1, b.m[4],  a2*b.m[8]));
        c.m[i*4+1] = fmaf(a0, b.m[1], fmaf(a1, b.m[5],  a2*b.m[9]));
        c.m[i*4+2] = fmaf(a0, b.m[2], fmaf(a1, b.m[6],  a2*b.m[10]));
        c.m[i*4+3] = fmaf(a0, b.m[3], fmaf(a1, b.m[7],  fmaf(a2, b.m[11], a.m[i*4+3])));
    }
    return c;
}

// lane-wise pull of an RT from (lane - off) within the wave
__device__ inline RT rt_shfl_up(const RT& a, int off) {
    RT r;
#pragma unroll
    for (int i = 0; i < 12; ++i) r.m[i] = __shfl_up(a.m[i], off, 64);
    return r;
}

// Accurate trig kept on purpose: the 4096-long compose chain amplifies per-HT
// error; absmax margin vs threshold is only ~2.2x.
__device__ inline RT local_ht(const float* __restrict__ dof) {
    float phi = dof[0], th = dof[1];
    float d = fmaf(0.25f, tanhf(dof[2]), 1.5f);
    float sp, cp, st, ct;
    sincosf(phi, &sp, &cp);
    sincosf(th,  &st, &ct);
    RT h;
    h.m[0] = cp*ct; h.m[1] = -sp; h.m[2]  = cp*st; h.m[3]  = d*cp*ct;
    h.m[4] = sp*ct; h.m[5] =  cp; h.m[6]  = sp*st; h.m[7]  = d*sp*ct;
    h.m[8] = -st;   h.m[9] = 0.f; h.m[10] = ct;    h.m[11] = -d*st;
    return h;
}

// ---------------- kernel 1a: per-segment inclusive scan (R3-verified) ----------
__global__ __launch_bounds__(SEG) void fk_scan(const float* __restrict__ dofs,
                                               float* __restrict__ Tx,
                                               float* __restrict__ Ty,
                                               float* __restrict__ Tz,
                                               float4* __restrict__ S0,
                                               float4* __restrict__ S1,
                                               float4* __restrict__ S2) {
    const int pose = blockIdx.x >> 6;        // NSEG = 64
    const int seg  = blockIdx.x & (NSEG - 1);
    const int lane = threadIdx.x;
    const int g    = pose * A_ATOMS + seg * SEG + lane;

    RT v = local_ht(dofs + (size_t)g * 9);

    // inclusive wave scan, earlier lane on the LEFT
#pragma unroll
    for (int off = 1; off < 64; off <<= 1) {
        RT l = rt_shfl_up(v, off);
        if (lane >= off) v = rt_compose(l, v);
    }

    // segment-relative translation for this atom (all that apply needs)
    Tx[g] = v.m[3]; Ty[g] = v.m[7]; Tz[g] = v.m[11];

    // segment total (full RT)
    if (lane == 63) {
        int s = pose * NSEG + seg;
        S0[s] = make_float4(v.m[0], v.m[1], v.m[2],  v.m[3]);
        S1[s] = make_float4(v.m[4], v.m[5], v.m[6],  v.m[7]);
        S2[s] = make_float4(v.m[8], v.m[9], v.m[10], v.m[11]);
    }
}

// ---------------- kernel 1b: totals scan + apply + scatter (R3-verified) --------
__global__ __launch_bounds__(APPLY_T) void fk_apply(const int* __restrict__ kid,
                                                    const float* __restrict__ Tx,
                                                    const float* __restrict__ Ty,
                                                    const float* __restrict__ Tz,
                                                    const float4* __restrict__ S0,
                                                    const float4* __restrict__ S1,
                                                    const float4* __restrict__ S2,
                                                    float* __restrict__ X,
                                                    float* __restrict__ Y,
                                                    float* __restrict__ Z,
                                                    float* __restrict__ out) {
    __shared__ float4 e0[NSEG], e1[NSEG], e2[NSEG];

    const int pose = blockIdx.y;
    const int blk  = blockIdx.x;
    const int tid  = threadIdx.x;
    if (blk == 0 && tid == 0) out[pose] = 0.f;

    if (tid < 64) {      // exactly wave 0: all 64 lanes active for shuffles
        int s = pose * NSEG + tid;
        float4 a0 = S0[s], a1 = S1[s], a2 = S2[s];
        RT v;
        v.m[0]=a0.x; v.m[1]=a0.y; v.m[2]=a0.z;  v.m[3]=a0.w;
        v.m[4]=a1.x; v.m[5]=a1.y; v.m[6]=a1.z;  v.m[7]=a1.w;
        v.m[8]=a2.x; v.m[9]=a2.y; v.m[10]=a2.z; v.m[11]=a2.w;
#pragma unroll
        for (int off = 1; off < 64; off <<= 1) {
            RT l = rt_shfl_up(v, off);
            if (tid >= off) v = rt_compose(l, v);
        }
        // exclusive prefix: shift right by one, identity at segment 0
        RT ex = rt_shfl_up(v, 1);
        if (tid == 0) ex = rt_identity();
        e0[tid] = make_float4(ex.m[0], ex.m[1], ex.m[2],  ex.m[3]);
        e1[tid] = make_float4(ex.m[4], ex.m[5], ex.m[6],  ex.m[7]);
        e2[tid] = make_float4(ex.m[8], ex.m[9], ex.m[10], ex.m[11]);
    }
    __syncthreads();

    const int a = blk * APPLY_T + tid;         // coalesced; a>>6 wave-uniform -> LDS broadcast
    const int g = pose * A_ATOMS + a;
    float rx = Tx[g], ry = Ty[g], rz = Tz[g];
    float4 x0 = e0[a >> 6], x1 = e1[a >> 6], x2 = e2[a >> 6];
    float tx = fmaf(x0.x, rx, fmaf(x0.y, ry, fmaf(x0.z, rz, x0.w)));
    float ty = fmaf(x1.x, rx, fmaf(x1.y, ry, fmaf(x1.z, rz, x1.w)));
    float tz = fmaf(x2.x, rx, fmaf(x2.y, ry, fmaf(x2.z, rz, x2.w)));
    int dst = kid[g];
    X[dst] = tx; Y[dst] = ty; Z[dst] = tz;
}

// ---------------- kernel 2: LJ, 4 j-tiles per block (128x512 strip) --------------
// R4 diagnosis: 2112 one-tile blocks were latency-bound (VALUBusy 17%, occ 28%,
// ~10k stall cycles of per-block fixed cost per ~2k busy). Amortize: each block
// owns one i-tile and a group of 4 aligned j-tiles -> 576 blocks, 4x work each.
// i-register fill (the strided-LDS-read block) hoisted out of the j-loop;
// next j-tile's global loads issue BEFORE compute (latency hides under the
// 64-pair loop), LDS write after the barrier. Inner compute loops unchanged.
__global__ __launch_bounds__(256) void lj_kernel(const float* __restrict__ X,
                                                 const float* __restrict__ Y,
                                                 const float* __restrict__ Z,
                                                 float* __restrict__ out) {
    const int pose = blockIdx.y;
    // map blockIdx.x -> (bi, jg): row bi has NJG - bi/JG aligned j-groups
    int rr = blockIdx.x, bi = 0;
    while (rr >= NJG - (bi >> 2)) { rr -= NJG - (bi >> 2); ++bi; }
    const int jg = (bi >> 2) + rr;           // absolute j-group (j-tiles jg*4 .. jg*4+3)
    // first valid t in this group (skip j-tiles left of the diagonal)
    const int t0 = (jg == (bi >> 2)) ? (bi & 3) : 0;

    __shared__ float sxi[TILE], syi[TILE], szi[TILE];
    __shared__ float sxj[TILE], syj[TILE], szj[TILE];

    const int tid = threadIdx.x;
    const float* Xp = X + pose * A_ATOMS;
    const float* Yp = Y + pose * A_ATOMS;
    const float* Zp = Z + pose * A_ATOMS;

    if (tid < TILE) {
        int gi = bi * TILE + tid;
        sxi[tid] = Xp[gi]; syi[tid] = Yp[gi]; szi[tid] = Zp[gi];
    } else {
        int t = tid - TILE;
        int gj = (jg * JG + t0) * TILE + t;
        sxj[t] = Xp[gj]; syj[t] = Yp[gj]; szj[t] = Zp[gj];
    }
    __syncthreads();

    // 16 i-groups x 16 j-groups; each thread: 8 i-rows x 8 j-cols in registers
    const int i0 = (tid & 15) * 8;
    const int j0 = (tid >> 4) * 8;

    const float SIG2 = c_SIGMA2, SOFT = c_R2SOFT;

    // i-registers: loaded ONCE for the whole strip (was per-tile in R4)
    float xi[8], yi[8], zi[8];
#pragma unroll
    for (int k = 0; k < 8; ++k) {
        xi[k] = sxi[i0 + k]; yi[k] = syi[i0 + k]; zi[k] = szi[i0 + k];
    }

    float acc = 0.f;

    for (int t = t0; t < JG; ++t) {
        const int bj = jg * JG + t;

        // issue next j-tile's global loads now; LDS write happens after the barrier
        float px, py, pz;
        if (t < JG - 1 && tid >= TILE) {
            int gj = (bj + 1) * TILE + (tid - TILE);
            px = Xp[gj]; py = Yp[gj]; pz = Zp[gj];
        }

        if (bi != bj) {
            // off-diagonal tile: packed fp32 pairs -> v_pk_fma_f32 candidates
            v2f xj2[4], yj2[4], zj2[4];
#pragma unroll
            for (int p = 0; p < 4; ++p) {
                xj2[p] = (v2f){sxj[j0 + 2*p], sxj[j0 + 2*p + 1]};
                yj2[p] = (v2f){syj[j0 + 2*p], syj[j0 + 2*p + 1]};
                zj2[p] = (v2f){szj[j0 + 2*p], szj[j0 + 2*p + 1]};
            }
            const v2f soft2 = (v2f){SOFT, SOFT};
            v2f acc2 = (v2f){0.f, 0.f};
#pragma unroll
            for (int p = 0; p < 4; ++p) {
#pragma unroll
                for (int k = 0; k < 8; ++k) {
                    v2f dx = xi[k] - xj2[p];
                    v2f dy = yi[k] - yj2[p];
                    v2f dz = zi[k] - zj2[p];
                    v2f r2 = __builtin_elementwise_fma(dx, dx,
                             __builtin_elementwise_fma(dy, dy,
                             __builtin_elementwise_fma(dz, dz, soft2)));
                    v2f rc = (v2f){__builtin_amdgcn_rcpf(r2.x), __builtin_amdgcn_rcpf(r2.y)};
                    v2f tt = SIG2 * rc;
                    v2f i6 = tt * tt * tt;
                    acc2 += __builtin_elementwise_fma(i6, i6, -i6);   // inv12 - inv6
                }
            }
            acc += acc2.x + acc2.y;
        } else {
            // diagonal tile: keep only i < j (scalar masked path)
            float xj[8], yj[8], zj[8];
#pragma unroll
            for (int k = 0; k < 8; ++k) {
                xj[k] = sxj[j0 + k]; yj[k] = syj[j0 + k]; zj[k] = szj[j0 + k];
            }
#pragma unroll
            for (int jj = 0; jj < 8; ++jj) {
                int j = j0 + jj;
#pragma unroll
                for (int k = 0; k < 8; ++k) {
                    float dx = xi[k] - xj[jj], dy = yi[k] - yj[jj], dz = zi[k] - zj[jj];
                    float r2 = fmaf(dx, dx, fmaf(dy, dy, fmaf(dz, dz, SOFT)));
                    float tt = SIG2 * __builtin_amdgcn_rcpf(r2);
                    float i6 = tt * tt * tt;
                    float hh = fmaf(i6, i6, -i6);
                    acc += ((i0 + k) < j) ? hh : 0.f;
                }
            }
        }

        if (t < JG - 1) {
            __syncthreads();                       // everyone done reading sxj
            if (tid >= TILE) {
                int tl = tid - TILE;
                sxj[tl] = px; syj[tl] = py; szj[tl] = pz;
            }
            __syncthreads();                       // next tile staged
        }
    }
    acc *= c_4EPS;

    // wave64 reduce then cross-wave via LDS
#pragma unroll
    for (int off = 32; off > 0; off >>= 1) acc += __shfl_down(acc, off, 64);

    __shared__ float wsum[4];
    int lane = tid & 63, wid = tid >> 6;
    if (lane == 0) wsum[wid] = acc;
    __syncthreads();
    if (tid == 0) {
        float s = wsum[0] + wsum[1] + wsum[2] + wsum[3];
        atomicAdd(out + pose, s);
    }
}

// ---------------- launch ----------------
extern "C" void kernel_launch(void* const* d_in, const int* in_sizes, int n_in,
                              void* d_out, int out_size, void* d_ws, size_t ws_size,
                              hipStream_t stream) {
    (void)in_sizes; (void)n_in; (void)out_size; (void)ws_size;
    const float* dofs = (const float*)d_in[0];
    const int*   kid  = (const int*)d_in[2];
    float*       out  = (float*)d_out;

    // workspace layout (16B-aligned), R3-verified:
    //   X,Y,Z:       3 * N_TOT floats (final coords, scattered)   192 KB
    //   Tx,Ty,Tz:    3 * N_TOT floats (segment-relative transl.)  192 KB
    //   S0,S1,S2:    3 * P*NSEG float4 (segment totals)            12 KB
    float* X  = (float*)d_ws;
    float* Y  = X + N_TOT;
    float* Z  = Y + N_TOT;
    float* Tx = Z + N_TOT;
    float* Ty = Tx + N_TOT;
    float* Tz = Ty + N_TOT;
    float4* S0 = (float4*)(Tz + N_TOT);
    float4* S1 = S0 + P_POSES * NSEG;
    float4* S2 = S1 + P_POSES * NSEG;

    fk_scan<<<P_POSES * NSEG, SEG, 0, stream>>>(dofs, Tx, Ty, Tz, S0, S1, S2);
    dim3 agrid(APPLY_B, P_POSES);
    fk_apply<<<agrid, APPLY_T, 0, stream>>>(kid, Tx, Ty, Tz, S0, S1, S2, X, Y, Z, out);
    dim3 grid(NSTRIPS, P_POSES);
    lj_kernel<<<grid, 256, 0, stream>>>(X, Y, Z, out);
}